// Round 1
// baseline (62.034 us; speedup 1.0000x reference)
//
#include <hip/hip_runtime.h>

// Decoder: piecewise-linear curve eval.
// segment_x, segment_y: [B=8, N+1=33] fp32. Output: [B, S=196608] fp32.
//
// Reference semantics:
//  1) fix x order = running max along segment axis; y carried from the
//     position achieving the max (ties keep later entry).
//  2) per pixel x_in=(s+1)/S, select segment j = largest j in [0,31] with
//     x[j] <= x_in (j=0 if x_in < x[1], j=31 if x_in >= x[31]) -- this is
//     exactly what the reference masked-sum computes, clamps included.
//  3) out = ratio_j*(x_in - x_j) + y_j, ratio_j = (y[j+1]-y[j]) /
//     (d==0 ? 1e-4 : d), d = x[j+1]-x[j].

constexpr int S = 196608;      // 3*256*256
constexpr int NSEG = 32;       // 33 knots
constexpr int ELEMS_PER_THREAD = 4;
constexpr int BLOCK = 256;
constexpr int ELEMS_PER_BLOCK = BLOCK * ELEMS_PER_THREAD;  // 1024

__global__ __launch_bounds__(BLOCK) void decoder_kernel(
    const float* __restrict__ seg_x,
    const float* __restrict__ seg_y,
    float* __restrict__ out)
{
    __shared__ float xs[NSEG + 1];
    __shared__ float ys[NSEG + 1];
    __shared__ float ratio[NSEG];

    const int b = blockIdx.y;
    const int tid = threadIdx.x;

    // Running-max fix of the knot list (33 elems; trivial, one lane).
    if (tid == 0) {
        const float* px = seg_x + b * (NSEG + 1);
        const float* py = seg_y + b * (NSEG + 1);
        float cx = px[0];
        float cy = py[0];
        xs[0] = cx; ys[0] = cy;
        for (int i = 1; i <= NSEG; ++i) {
            float xi = px[i];
            float yi = py[i];
            if (xi >= cx) { cx = xi; cy = yi; }  // ties take the later entry
            xs[i] = cx; ys[i] = cy;
        }
    }
    __syncthreads();

    if (tid < NSEG) {
        float d = xs[tid + 1] - xs[tid];
        if (d == 0.0f) d = 0.0001f;
        ratio[tid] = (ys[tid + 1] - ys[tid]) / d;
    }
    __syncthreads();

    const int s_base = blockIdx.x * ELEMS_PER_BLOCK + tid * ELEMS_PER_THREAD;

    float4 res;
    float* rp = &res.x;
#pragma unroll
    for (int e = 0; e < ELEMS_PER_THREAD; ++e) {
        const int s = s_base + e;
        // exact match with reference: arange(1..S) / S in fp32
        const float xin = (float)(s + 1) / (float)S;

        // branchless: j = #{ k in [1,31] : xs[k] <= xin }
        int j = 0;
#pragma unroll
        for (int k = 1; k < NSEG; ++k) {
            j += (xin >= xs[k]) ? 1 : 0;   // broadcast LDS read, free
        }
        rp[e] = fmaf(ratio[j], xin - xs[j], ys[j]);
    }

    // coalesced 16B store
    *reinterpret_cast<float4*>(&out[(size_t)b * S + s_base]) = res;
}

extern "C" void kernel_launch(void* const* d_in, const int* in_sizes, int n_in,
                              void* d_out, int out_size, void* d_ws, size_t ws_size,
                              hipStream_t stream) {
    const float* seg_x = (const float*)d_in[0];
    const float* seg_y = (const float*)d_in[1];
    float* out = (float*)d_out;

    dim3 grid(S / ELEMS_PER_BLOCK, 8);  // (192, 8)
    decoder_kernel<<<grid, BLOCK, 0, stream>>>(seg_x, seg_y, out);
}

// Round 2
// 60.569 us; speedup vs baseline: 1.0242x; 1.0242x over previous
//
#include <hip/hip_runtime.h>

// Decoder: piecewise-linear curve eval.
// segment_x, segment_y: [B=8, N+1=33] fp32. Output: [B, S=196608] fp32.
//
// Semantics (proven equivalent to the reference masked-sum in round 0):
//  1) fixed knots = inclusive running-max scan of x (ties keep later entry),
//     y carried from the winning position.
//  2) per pixel xin=(s+1)/S, j = largest j in [0,31] with xs[j] <= xin
//     (== branchless count of xs[k] <= xin over k=1..31).
//  3) out = ratio[j]*(xin - xs[j]) + ys[j], ratio = dy / (dx==0 ? 1e-4 : dx).

constexpr int S = 196608;   // 3*256*256
constexpr int NK = 33;      // knots
constexpr int NSEG = 32;
constexpr int BLOCK = 256;
constexpr int EPT = 8;             // elems per thread
constexpr int EPB = BLOCK * EPT;   // 2048 elems per block
constexpr int HALF = BLOCK * 4;    // 1024: two contiguous float4 tiles

__global__ __launch_bounds__(BLOCK) void decoder_kernel(
    const float* __restrict__ seg_x,
    const float* __restrict__ seg_y,
    float* __restrict__ out)
{
    __shared__ float xs[NK];
    __shared__ float ys[NK];
    __shared__ float ratio[NSEG];

    const int b = blockIdx.y;
    const int tid = threadIdx.x;

    // ---- knot prep: wave 0 only, parallel shuffle scan ----
    if (tid < 64) {
        float x = 0.0f, y = 0.0f;
        if (tid < NK) {
            x = seg_x[b * NK + tid];
            y = seg_y[b * NK + tid];
        }
        // inclusive running-max scan; combine(prev,cur): keep cur if
        // cur.x >= prev.x (later entry wins ties), else take prev.
#pragma unroll
        for (int d = 1; d < 64; d <<= 1) {
            float ox = __shfl_up(x, d);
            float oy = __shfl_up(y, d);
            if (tid >= d && x < ox) { x = ox; y = oy; }
        }
        float xn = __shfl_down(x, 1);
        float yn = __shfl_down(y, 1);
        if (tid < NK) { xs[tid] = x; ys[tid] = y; }
        if (tid < NSEG) {
            float dx = xn - x;
            if (dx == 0.0f) dx = 0.0001f;
            ratio[tid] = (yn - y) / dx;
        }
    }
    __syncthreads();

    // hoist knot x's into registers (broadcast LDS reads, done once,
    // reused for 8 elements of compares)
    float xr[NSEG];
#pragma unroll
    for (int k = 0; k < NSEG; ++k) xr[k] = xs[k];

    const size_t obase = (size_t)b * S;

#pragma unroll
    for (int h = 0; h < 2; ++h) {
        const int s0 = blockIdx.x * EPB + h * HALF + tid * 4;
        float tmp[4];
#pragma unroll
        for (int e = 0; e < 4; ++e) {
            // exact match with reference: arange(1..S)/S in fp32 division
            const float xin = (float)(s0 + e + 1) / (float)S;
            int j = 0;
#pragma unroll
            for (int k = 1; k < NSEG; ++k) {
                j += (xin >= xr[k]) ? 1 : 0;   // register compares
            }
            // dynamic-index fetches stay in LDS (conflict-free / broadcast)
            tmp[e] = fmaf(ratio[j], xin - xs[j], ys[j]);
        }
        float4 v;
        v.x = tmp[0]; v.y = tmp[1]; v.z = tmp[2]; v.w = tmp[3];
        *reinterpret_cast<float4*>(&out[obase + s0]) = v;  // coalesced 16B
    }
}

extern "C" void kernel_launch(void* const* d_in, const int* in_sizes, int n_in,
                              void* d_out, int out_size, void* d_ws, size_t ws_size,
                              hipStream_t stream) {
    const float* seg_x = (const float*)d_in[0];
    const float* seg_y = (const float*)d_in[1];
    float* out = (float*)d_out;

    dim3 grid(S / EPB, 8);  // (96, 8)
    decoder_kernel<<<grid, BLOCK, 0, stream>>>(seg_x, seg_y, out);
}